// Round 1
// baseline (1286.194 us; speedup 1.0000x reference)
//
#include <hip/hip_runtime.h>

#define IN_DIM 256
#define HID 64

// ---------------------------------------------------------------------------
// 1) deg[i] = 1.0 (self loop contribution)
__global__ void __launch_bounds__(256) k_init_deg(float* __restrict__ deg, int N) {
    int i = blockIdx.x * 256 + threadIdx.x;
    int stride = gridDim.x * 256;
    for (; i < N; i += stride) deg[i] = 1.0f;
}

// 2) deg[col[e]] += 1 for every edge
__global__ void __launch_bounds__(256) k_count_deg(const int* __restrict__ col,
                                                   float* __restrict__ deg, int E) {
    int i = blockIdx.x * 256 + threadIdx.x;
    int stride = gridDim.x * 256;
    for (; i < E; i += stride) atomicAdd(&deg[col[i]], 1.0f);
}

// 3) dinv[i] = rsqrt(deg[i])   (deg >= 1 always, self-loops guarantee it)
__global__ void __launch_bounds__(256) k_rsqrt(const float* __restrict__ deg,
                                               float* __restrict__ dinv, int N) {
    int i = blockIdx.x * 256 + threadIdx.x;
    int stride = gridDim.x * 256;
    for (; i < N; i += stride) dinv[i] = __frsqrt_rn(deg[i]);
}

// 4) xt = x @ W  (fp32, W staged in LDS, one wave per node, lane = out column)
//    Fused epilogue: out = xt * dinv^2 + b   (self-loop message + bias)
__global__ void __launch_bounds__(256) k_gemm(const float* __restrict__ x,
                                              const float* __restrict__ W,
                                              const float* __restrict__ dinv,
                                              const float* __restrict__ b,
                                              float* __restrict__ xt,
                                              float* __restrict__ out, int N) {
    __shared__ float Wl[IN_DIM * HID];  // 64 KB -> 2 blocks/CU
    for (int i = threadIdx.x; i < IN_DIM * HID / 4; i += 256)
        ((float4*)Wl)[i] = ((const float4*)W)[i];
    __syncthreads();

    const int wave = threadIdx.x >> 6;
    const int lane = threadIdx.x & 63;
    const float bl = b[lane];

    for (int n = blockIdx.x * 4 + wave; n < N; n += gridDim.x * 4) {
        const float* xr = x + (size_t)n * IN_DIM;
        float acc = 0.f;
#pragma unroll 4
        for (int k0 = 0; k0 < IN_DIM; k0 += 4) {
            float4 xv = *(const float4*)(xr + k0);  // wave-uniform, L1 broadcast
            acc = fmaf(xv.x, Wl[(k0 + 0) * HID + lane], acc);
            acc = fmaf(xv.y, Wl[(k0 + 1) * HID + lane], acc);
            acc = fmaf(xv.z, Wl[(k0 + 2) * HID + lane], acc);
            acc = fmaf(xv.w, Wl[(k0 + 3) * HID + lane], acc);
        }
        const size_t o = (size_t)n * HID + lane;
        xt[o] = acc;
        const float di = dinv[n];
        out[o] = fmaf(acc, di * di, bl);  // init accumulator with self-loop + bias
    }
}

// 5) edge scatter: out[col] += xt[row] * dinv[row]*dinv[col]
//    one wave per edge, lane = column
__global__ void __launch_bounds__(256) k_scatter(const int* __restrict__ row,
                                                 const int* __restrict__ col,
                                                 const float* __restrict__ dinv,
                                                 const float* __restrict__ xt,
                                                 float* __restrict__ out, int E) {
    const int lane = threadIdx.x & 63;
    int w = blockIdx.x * (256 >> 6) + (threadIdx.x >> 6);
    const int nw = gridDim.x * (256 >> 6);
    for (int e = w; e < E; e += nw) {
        const int r = row[e];
        const int c = col[e];
        const float nrm = dinv[r] * dinv[c];
        const float v = xt[(size_t)r * HID + lane] * nrm;
        atomicAdd(&out[(size_t)c * HID + lane], v);
    }
}

// 6) ReLU in place (float4)
__global__ void __launch_bounds__(256) k_relu(float4* __restrict__ out, int n4) {
    int i = blockIdx.x * 256 + threadIdx.x;
    if (i < n4) {
        float4 v = out[i];
        v.x = fmaxf(v.x, 0.f);
        v.y = fmaxf(v.y, 0.f);
        v.z = fmaxf(v.z, 0.f);
        v.w = fmaxf(v.w, 0.f);
        out[i] = v;
    }
}

extern "C" void kernel_launch(void* const* d_in, const int* in_sizes, int n_in,
                              void* d_out, int out_size, void* d_ws, size_t ws_size,
                              hipStream_t stream) {
    const float* x  = (const float*)d_in[0];
    const int*   ei = (const int*)d_in[1];
    const float* W  = (const float*)d_in[2];
    const float* b  = (const float*)d_in[3];
    float* out = (float*)d_out;

    const int N = in_sizes[0] / IN_DIM;
    const int E = in_sizes[1] / 2;
    const int* row = ei;      // edge_index[0] = sources
    const int* col = ei + E;  // edge_index[1] = destinations

    // workspace layout: deg[N] | dinv[N] | xt[N*HID]   (~26.4 MB)
    float* deg  = (float*)d_ws;
    float* dinv = deg + N;
    float* xt   = dinv + N;

    k_init_deg<<<(N + 255) / 256, 256, 0, stream>>>(deg, N);
    k_count_deg<<<2048, 256, 0, stream>>>(col, deg, E);
    k_rsqrt<<<(N + 255) / 256, 256, 0, stream>>>(deg, dinv, N);
    k_gemm<<<512, 256, 0, stream>>>(x, W, dinv, b, xt, out, N);
    k_scatter<<<2048, 256, 0, stream>>>(row, col, dinv, xt, out, E);
    k_relu<<<(N * HID / 4 + 255) / 256, 256, 0, stream>>>((float4*)out, N * HID / 4);
}

// Round 2
// 1039.599 us; speedup vs baseline: 1.2372x; 1.2372x over previous
//
#include <hip/hip_runtime.h>

#define IN_DIM 256
#define HID 64
#define CHUNK 2048  // elements scanned per block in k_scan1 (256 thr x 8)

// ---------------------------------------------------------------------------
// 1) cnt[i] = 0
__global__ void __launch_bounds__(256) k_zero(int* __restrict__ cnt, int N) {
    int i = blockIdx.x * 256 + threadIdx.x;
    int stride = gridDim.x * 256;
    for (; i < N; i += stride) cnt[i] = 0;
}

// 2) histogram of destinations: cnt[col[e]]++
__global__ void __launch_bounds__(256) k_hist(const int* __restrict__ col,
                                              int* __restrict__ cnt, int E) {
    int i = blockIdx.x * 256 + threadIdx.x;
    int stride = gridDim.x * 256;
    for (; i < E; i += stride) atomicAdd(&cnt[col[i]], 1);
}

// 3a) per-chunk exclusive partial scan + chunk sums
__global__ void __launch_bounds__(256) k_scan1(const int* __restrict__ cnt,
                                               int* __restrict__ part,
                                               int* __restrict__ chunkSum, int N) {
    __shared__ int tmp[256];
    const int tid = threadIdx.x;
    const int base = blockIdx.x * CHUNK + tid * 8;
    int v[8];
    int s = 0;
#pragma unroll
    for (int t = 0; t < 8; ++t) {
        int i = base + t;
        v[t] = (i < N) ? cnt[i] : 0;
        s += v[t];
    }
    tmp[tid] = s;
    __syncthreads();
    for (int d = 1; d < 256; d <<= 1) {  // Hillis-Steele inclusive scan
        int val = (tid >= d) ? tmp[tid - d] : 0;
        __syncthreads();
        tmp[tid] += val;
        __syncthreads();
    }
    int run = tmp[tid] - s;  // exclusive base for this thread
#pragma unroll
    for (int t = 0; t < 8; ++t) {
        int i = base + t;
        if (i < N) part[i] = run;
        run += v[t];
    }
    if (tid == 255) chunkSum[blockIdx.x] = tmp[255];
}

// 3b) serial scan of chunk sums (tiny: ~49 entries)
__global__ void k_scan2(const int* __restrict__ chunkSum, int* __restrict__ chunkOff, int nch) {
    if (threadIdx.x == 0 && blockIdx.x == 0) {
        int run = 0;
        for (int c = 0; c < nch; ++c) { chunkOff[c] = run; run += chunkSum[c]; }
    }
}

// 3c) finalize rowptr, cursor copy, dinv = rsqrt(deg+1)
__global__ void __launch_bounds__(256) k_scan3(const int* __restrict__ cnt,
                                               const int* __restrict__ part,
                                               const int* __restrict__ chunkOff,
                                               int* __restrict__ rowptr, int* __restrict__ cursor,
                                               float* __restrict__ dinv, int N, int E) {
    int i = blockIdx.x * 256 + threadIdx.x;
    int stride = gridDim.x * 256;
    for (; i < N; i += stride) {
        int r = part[i] + chunkOff[i >> 11];  // CHUNK = 2048 = 1<<11
        rowptr[i] = r;
        cursor[i] = r;
        dinv[i] = __frsqrt_rn((float)(cnt[i] + 1));
    }
    if (blockIdx.x == 0 && threadIdx.x == 0) rowptr[N] = E;
}

// 4) xs = (x @ W) * dinv[n]   (fp32, W in LDS, wave per node, lane = column)
__global__ void __launch_bounds__(256) k_gemm(const float* __restrict__ x,
                                              const float* __restrict__ W,
                                              const float* __restrict__ dinv,
                                              float* __restrict__ xs, int N) {
    __shared__ float Wl[IN_DIM * HID];  // 64 KB -> 2 blocks/CU
    for (int i = threadIdx.x; i < IN_DIM * HID / 4; i += 256)
        ((float4*)Wl)[i] = ((const float4*)W)[i];
    __syncthreads();

    const int wave = threadIdx.x >> 6;
    const int lane = threadIdx.x & 63;

    for (int n = blockIdx.x * 4 + wave; n < N; n += gridDim.x * 4) {
        const float* xr = x + (size_t)n * IN_DIM;
        float acc = 0.f;
#pragma unroll 4
        for (int k0 = 0; k0 < IN_DIM; k0 += 4) {
            float4 xv = *(const float4*)(xr + k0);  // wave-uniform, broadcast
            acc = fmaf(xv.x, Wl[(k0 + 0) * HID + lane], acc);
            acc = fmaf(xv.y, Wl[(k0 + 1) * HID + lane], acc);
            acc = fmaf(xv.z, Wl[(k0 + 2) * HID + lane], acc);
            acc = fmaf(xv.w, Wl[(k0 + 3) * HID + lane], acc);
        }
        xs[(size_t)n * HID + lane] = acc * dinv[n];
    }
}

// 5) bucket edges by destination: eRow[cursor[col]++] = row
__global__ void __launch_bounds__(256) k_bucket(const int* __restrict__ row,
                                                const int* __restrict__ col,
                                                int* __restrict__ cursor,
                                                int* __restrict__ eRow, int E) {
    int i = blockIdx.x * 256 + threadIdx.x;
    int stride = gridDim.x * 256;
    for (; i < E; i += stride) {
        int pos = atomicAdd(&cursor[col[i]], 1);
        eRow[pos] = row[i];
    }
}

// 6) gather-aggregate: out[n] = relu(dinv[n]*(xs[n] + sum_{r in nbr(n)} xs[r]) + b)
//    one wave per node, lane = hidden column; no atomics.
__global__ void __launch_bounds__(256) k_aggregate(const int* __restrict__ rowptr,
                                                   const int* __restrict__ eRow,
                                                   const float* __restrict__ xs,
                                                   const float* __restrict__ dinv,
                                                   const float* __restrict__ b,
                                                   float* __restrict__ out, int N) {
    const int lane = threadIdx.x & 63;
    const int n = blockIdx.x * 4 + (threadIdx.x >> 6);
    if (n >= N) return;
    const float bl = b[lane];

    const int s = rowptr[n];
    const int e = rowptr[n + 1];
    float acc = xs[(size_t)n * HID + lane];  // self-loop term (xs already has dinv[n])
    float a0 = 0.f, a1 = 0.f, a2 = 0.f, a3 = 0.f;
    int j = s;
    for (; j + 3 < e; j += 4) {
        int r0 = eRow[j], r1 = eRow[j + 1], r2 = eRow[j + 2], r3 = eRow[j + 3];
        a0 += xs[(size_t)r0 * HID + lane];
        a1 += xs[(size_t)r1 * HID + lane];
        a2 += xs[(size_t)r2 * HID + lane];
        a3 += xs[(size_t)r3 * HID + lane];
    }
    for (; j < e; ++j) acc += xs[(size_t)eRow[j] * HID + lane];
    acc += (a0 + a1) + (a2 + a3);

    out[(size_t)n * HID + lane] = fmaxf(fmaf(acc, dinv[n], bl), 0.f);
}

extern "C" void kernel_launch(void* const* d_in, const int* in_sizes, int n_in,
                              void* d_out, int out_size, void* d_ws, size_t ws_size,
                              hipStream_t stream) {
    const float* x  = (const float*)d_in[0];
    const int*   ei = (const int*)d_in[1];
    const float* W  = (const float*)d_in[2];
    const float* b  = (const float*)d_in[3];
    float* out = (float*)d_out;

    const int N = in_sizes[0] / IN_DIM;
    const int E = in_sizes[1] / 2;
    const int* row = ei;      // edge_index[0] = sources
    const int* col = ei + E;  // edge_index[1] = destinations
    const int nch = (N + CHUNK - 1) / CHUNK;

    // workspace layout (4-byte units):
    // cnt[N] | part[N] | rowptr[N+1] | cursor[N] | chunkSum[64] | chunkOff[64]
    // | dinv[N] | xs[N*HID] | eRow[E]
    int*   cnt      = (int*)d_ws;
    int*   part     = cnt + N;
    int*   rowptr   = part + N;
    int*   cursor   = rowptr + (N + 1);
    int*   chunkSum = cursor + N;
    int*   chunkOff = chunkSum + 64;
    float* dinv     = (float*)(chunkOff + 64);
    float* xs       = dinv + N;
    int*   eRow     = (int*)(xs + (size_t)N * HID);

    k_zero<<<(N + 255) / 256, 256, 0, stream>>>(cnt, N);
    k_hist<<<2048, 256, 0, stream>>>(col, cnt, E);
    k_scan1<<<nch, 256, 0, stream>>>(cnt, part, chunkSum, N);
    k_scan2<<<1, 64, 0, stream>>>(chunkSum, chunkOff, nch);
    k_scan3<<<(N + 255) / 256, 256, 0, stream>>>(cnt, part, chunkOff, rowptr, cursor, dinv, N, E);
    k_gemm<<<1024, 256, 0, stream>>>(x, W, dinv, xs, N);
    k_bucket<<<2048, 256, 0, stream>>>(row, col, cursor, eRow, E);
    k_aggregate<<<(N + 3) / 4, 256, 0, stream>>>(rowptr, eRow, xs, dinv, b, out, N);
}

// Round 3
// 769.986 us; speedup vs baseline: 1.6704x; 1.3502x over previous
//
#include <hip/hip_runtime.h>

#define IN_DIM 256
#define HID 64
#define CHUNK 2048  // elements scanned per block in k_scan1 (256 thr x 8)

// ---------------------------------------------------------------------------
// 1) cnt[i] = 0
__global__ void __launch_bounds__(256) k_zero(int* __restrict__ cnt, int N) {
    int i = blockIdx.x * 256 + threadIdx.x;
    int stride = gridDim.x * 256;
    for (; i < N; i += stride) cnt[i] = 0;
}

// 2) histogram of destinations: cnt[col[e]]++
__global__ void __launch_bounds__(256) k_hist(const int* __restrict__ col,
                                              int* __restrict__ cnt, int E) {
    int i = blockIdx.x * 256 + threadIdx.x;
    int stride = gridDim.x * 256;
    for (; i < E; i += stride) atomicAdd(&cnt[col[i]], 1);
}

// 3a) per-chunk exclusive partial scan + chunk sums
__global__ void __launch_bounds__(256) k_scan1(const int* __restrict__ cnt,
                                               int* __restrict__ part,
                                               int* __restrict__ chunkSum, int N) {
    __shared__ int tmp[256];
    const int tid = threadIdx.x;
    const int base = blockIdx.x * CHUNK + tid * 8;
    int v[8];
    int s = 0;
#pragma unroll
    for (int t = 0; t < 8; ++t) {
        int i = base + t;
        v[t] = (i < N) ? cnt[i] : 0;
        s += v[t];
    }
    tmp[tid] = s;
    __syncthreads();
    for (int d = 1; d < 256; d <<= 1) {  // Hillis-Steele inclusive scan
        int val = (tid >= d) ? tmp[tid - d] : 0;
        __syncthreads();
        tmp[tid] += val;
        __syncthreads();
    }
    int run = tmp[tid] - s;  // exclusive base for this thread
#pragma unroll
    for (int t = 0; t < 8; ++t) {
        int i = base + t;
        if (i < N) part[i] = run;
        run += v[t];
    }
    if (tid == 255) chunkSum[blockIdx.x] = tmp[255];
}

// 3b) serial scan of chunk sums (tiny: ~49 entries)
__global__ void k_scan2(const int* __restrict__ chunkSum, int* __restrict__ chunkOff, int nch) {
    if (threadIdx.x == 0 && blockIdx.x == 0) {
        int run = 0;
        for (int c = 0; c < nch; ++c) { chunkOff[c] = run; run += chunkSum[c]; }
    }
}

// 3c) finalize rowptr, cursor copy, dinv = rsqrt(deg+1)
__global__ void __launch_bounds__(256) k_scan3(const int* __restrict__ cnt,
                                               const int* __restrict__ part,
                                               const int* __restrict__ chunkOff,
                                               int* __restrict__ rowptr, int* __restrict__ cursor,
                                               float* __restrict__ dinv, int N, int E) {
    int i = blockIdx.x * 256 + threadIdx.x;
    int stride = gridDim.x * 256;
    for (; i < N; i += stride) {
        int r = part[i] + chunkOff[i >> 11];  // CHUNK = 2048 = 1<<11
        rowptr[i] = r;
        cursor[i] = r;
        dinv[i] = __frsqrt_rn((float)(cnt[i] + 1));
    }
    if (blockIdx.x == 0 && threadIdx.x == 0) rowptr[N] = E;
}

// 4) xs = (x @ W) * dinv[n]
//    Register-tiled fp32 GEMM: block 256 thr (tdimM=32 x tdimN=8),
//    tile BM=256 nodes x 64 cols, TM=TN=8 -> 64 acc/thread.
//    LDS: xT[32][260] transposed+padded (40.6 KB tot) -> 1 LDS byte/FMA.
__global__ void __launch_bounds__(256) k_gemm(const float* __restrict__ x,
                                              const float* __restrict__ W,
                                              const float* __restrict__ dinv,
                                              float* __restrict__ xs, int N) {
    __shared__ float xT[32][260];  // [k][node], pad +4 keeps b128 16B-aligned, breaks 8-way
    __shared__ float Wl[32][64];   // [k][col]
    const int t = threadIdx.x;
    const int tmI = t >> 3;   // 0..31 -> node sub-tile
    const int tnI = t & 7;    // 0..7  -> col sub-tile
    const int nodeBase = blockIdx.x * 256;

    float acc[8][8] = {};

    for (int k0 = 0; k0 < IN_DIM; k0 += 32) {
        // stage W tile: 32 rows x 64 cols = 512 float4
#pragma unroll
        for (int i = 0; i < 2; ++i) {
            int flat = i * 256 + t;  // float4 index within tile
            float4 wv = ((const float4*)W)[k0 * 16 + flat];
            *(float4*)&Wl[flat >> 4][(flat & 15) << 2] = wv;
        }
        // stage x tile transposed: 256 nodes x 32 k
#pragma unroll
        for (int i = 0; i < 8; ++i) {
            int flat = i * 256 + t;       // 0..2047
            int n = flat >> 3;            // 0..255
            int kq = (flat & 7) << 2;     // 0,4,...,28
            int gn = nodeBase + n;
            if (gn >= N) gn = N - 1;      // clamp: duplicate last row, stores guarded
            float4 v = *(const float4*)(x + (size_t)gn * IN_DIM + k0 + kq);
            xT[kq + 0][n] = v.x;
            xT[kq + 1][n] = v.y;
            xT[kq + 2][n] = v.z;
            xT[kq + 3][n] = v.w;
        }
        __syncthreads();
#pragma unroll
        for (int k = 0; k < 32; ++k) {
            float xv[8], wv[8];
            *(float4*)&xv[0] = *(const float4*)&xT[k][tmI * 8];
            *(float4*)&xv[4] = *(const float4*)&xT[k][tmI * 8 + 4];
            *(float4*)&wv[0] = *(const float4*)&Wl[k][tnI * 8];
            *(float4*)&wv[4] = *(const float4*)&Wl[k][tnI * 8 + 4];
#pragma unroll
            for (int mi = 0; mi < 8; ++mi)
#pragma unroll
                for (int ni = 0; ni < 8; ++ni)
                    acc[mi][ni] = fmaf(xv[mi], wv[ni], acc[mi][ni]);
        }
        __syncthreads();
    }

#pragma unroll
    for (int mi = 0; mi < 8; ++mi) {
        int n = nodeBase + tmI * 8 + mi;
        if (n < N) {
            float d = dinv[n];
            float* dst = xs + (size_t)n * HID + tnI * 8;
            float4 o;
            o.x = acc[mi][0] * d; o.y = acc[mi][1] * d;
            o.z = acc[mi][2] * d; o.w = acc[mi][3] * d;
            *(float4*)dst = o;
            o.x = acc[mi][4] * d; o.y = acc[mi][5] * d;
            o.z = acc[mi][6] * d; o.w = acc[mi][7] * d;
            *(float4*)(dst + 4) = o;
        }
    }
}

// 5) bucket edges by destination: eRow[cursor[col]++] = row
__global__ void __launch_bounds__(256) k_bucket(const int* __restrict__ row,
                                                const int* __restrict__ col,
                                                int* __restrict__ cursor,
                                                int* __restrict__ eRow, int E) {
    int i = blockIdx.x * 256 + threadIdx.x;
    int stride = gridDim.x * 256;
    for (; i < E; i += stride) {
        int pos = atomicAdd(&cursor[col[i]], 1);
        eRow[pos] = row[i];
    }
}

// 6) gather-aggregate: out[n] = relu(dinv[n]*(xs[n] + sum_{r in nbr(n)} xs[r]) + b)
//    one wave per node, lane = hidden column; no atomics.
__global__ void __launch_bounds__(256) k_aggregate(const int* __restrict__ rowptr,
                                                   const int* __restrict__ eRow,
                                                   const float* __restrict__ xs,
                                                   const float* __restrict__ dinv,
                                                   const float* __restrict__ b,
                                                   float* __restrict__ out, int N) {
    const int lane = threadIdx.x & 63;
    const int n = blockIdx.x * 4 + (threadIdx.x >> 6);
    if (n >= N) return;
    const float bl = b[lane];

    const int s = rowptr[n];
    const int e = rowptr[n + 1];
    float acc = xs[(size_t)n * HID + lane];  // self-loop term (xs already has dinv[n])
    float a0 = 0.f, a1 = 0.f, a2 = 0.f, a3 = 0.f;
    int j = s;
    for (; j + 3 < e; j += 4) {
        int r0 = eRow[j], r1 = eRow[j + 1], r2 = eRow[j + 2], r3 = eRow[j + 3];
        a0 += xs[(size_t)r0 * HID + lane];
        a1 += xs[(size_t)r1 * HID + lane];
        a2 += xs[(size_t)r2 * HID + lane];
        a3 += xs[(size_t)r3 * HID + lane];
    }
    for (; j < e; ++j) acc += xs[(size_t)eRow[j] * HID + lane];
    acc += (a0 + a1) + (a2 + a3);

    out[(size_t)n * HID + lane] = fmaxf(fmaf(acc, dinv[n], bl), 0.f);
}

extern "C" void kernel_launch(void* const* d_in, const int* in_sizes, int n_in,
                              void* d_out, int out_size, void* d_ws, size_t ws_size,
                              hipStream_t stream) {
    const float* x  = (const float*)d_in[0];
    const int*   ei = (const int*)d_in[1];
    const float* W  = (const float*)d_in[2];
    const float* b  = (const float*)d_in[3];
    float* out = (float*)d_out;

    const int N = in_sizes[0] / IN_DIM;
    const int E = in_sizes[1] / 2;
    const int* row = ei;      // edge_index[0] = sources
    const int* col = ei + E;  // edge_index[1] = destinations
    const int nch = (N + CHUNK - 1) / CHUNK;

    // workspace layout (4-byte units):
    // cnt[N] | part[N] | rowptr[N+1] | cursor[N] | chunkSum[64] | chunkOff[64]
    // | dinv[N] | xs[N*HID] | eRow[E]
    int*   cnt      = (int*)d_ws;
    int*   part     = cnt + N;
    int*   rowptr   = part + N;
    int*   cursor   = rowptr + (N + 1);
    int*   chunkSum = cursor + N;
    int*   chunkOff = chunkSum + 64;
    float* dinv     = (float*)(chunkOff + 64);
    float* xs       = dinv + N;
    int*   eRow     = (int*)(xs + (size_t)N * HID);

    k_zero<<<(N + 255) / 256, 256, 0, stream>>>(cnt, N);
    k_hist<<<2048, 256, 0, stream>>>(col, cnt, E);
    k_scan1<<<nch, 256, 0, stream>>>(cnt, part, chunkSum, N);
    k_scan2<<<1, 64, 0, stream>>>(chunkSum, chunkOff, nch);
    k_scan3<<<(N + 255) / 256, 256, 0, stream>>>(cnt, part, chunkOff, rowptr, cursor, dinv, N, E);
    k_gemm<<<(N + 255) / 256, 256, 0, stream>>>(x, W, dinv, xs, N);
    k_bucket<<<2048, 256, 0, stream>>>(row, col, cursor, eRow, E);
    k_aggregate<<<(N + 3) / 4, 256, 0, stream>>>(rowptr, eRow, xs, dinv, b, out, N);
}